// Round 3
// baseline (326.720 us; speedup 1.0000x reference)
//
#include <hip/hip_runtime.h>

#define NT 256
#define TW 32
#define TH 16
#define IH (TH + 10)   // 26 h-pass rows
#define HP 33          // LDS row stride in float4 units
#define IMW 512
#define IMH 512
#define NBLK ((IMW / TW) * (IMH / TH) * 16)   // 8192

__device__ __forceinline__ float wave_reduce(float v) {
    #pragma unroll
    for (int off = 32; off > 0; off >>= 1)
        v += __shfl_down(v, off, 64);
    return v;
}

// LDS column swizzle: breaks the 4-way bank conflict of stride-4-float4 store
// lanes (bank base becomes all-8-distinct over cg) while keeping the v-pass
// consecutive-lane reads 2-way (free).
__device__ __forceinline__ int swz(int i) { return i ^ (i >> 3); }

// Gaussian 1-D weights for ws=11, sigma=1.5 (separable outer product == ref 2-D kernel)
#define G0 0.00102838f
#define G1 0.00759840f
#define G2 0.03600077f
#define G3 0.10936070f
#define G4 0.21300590f
#define G5 0.26601190f

__global__ __launch_bounds__(NT, 5) void ssim_main_kernel(
    const float* __restrict__ fused,
    const float* __restrict__ img_a,
    const float* __restrict__ img_b,
    float* __restrict__ acc_ws,          // [0]=sum, [1]=done-counter
    float* __restrict__ out,
    float invTwoN)
{
    // h-pass results, AoS float4: h4a = (p, a, b, pp), h4b = (aa, bb, pa, pb)
    __shared__ float4 h4a[IH * HP];
    __shared__ float4 h4b[IH * HP];
    __shared__ float red[NT / 64];

    const float g[11] = {G0, G1, G2, G3, G4, G5, G4, G3, G2, G1, G0};

    const int tid = threadIdx.x;
    const int x0 = blockIdx.x * TW;
    const int y0 = blockIdx.y * TH;
    const size_t ioff = (size_t)blockIdx.z * IMW * IMH;
    const float* Fp = fused + ioff;
    const float* Ap = img_a + ioff;
    const float* Bp = img_b + ioff;

    // ---------------- horizontal pass: global (L1/L2) -> registers -> LDS ----
    // task = (row r in [0,IH), col-group cg in [0,8)); 4 output cols per task.
    // Load 5 aligned float4 chunks at xbase = x0+4cg-8 (elements i=0..19, used
    // i in [3,17)). Products computed once per loaded element.
    if (tid < IH * 8) {
        const int r  = tid >> 3;
        const int cg = tid & 7;
        const int gy = y0 + r - 5;
        const bool yok = (gy >= 0) && (gy < IMH);

        float accs[4][8];
        #pragma unroll
        for (int k = 0; k < 4; ++k)
            #pragma unroll
            for (int q = 0; q < 8; ++q) accs[k][q] = 0.f;

        const int xbase = x0 + 4 * cg - 8;
        #pragma unroll
        for (int w = 0; w < 5; ++w) {
            const int xc = xbase + 4 * w;
            float4 p4 = {0.f, 0.f, 0.f, 0.f};
            float4 a4 = {0.f, 0.f, 0.f, 0.f};
            float4 b4 = {0.f, 0.f, 0.f, 0.f};
            if (yok && xc >= 0 && xc < IMW) {
                const size_t o = ((size_t)gy * IMW + xc) >> 2;  // float4 index
                p4 = ((const float4*)Fp)[o];
                a4 = ((const float4*)Ap)[o];
                b4 = ((const float4*)Bp)[o];
                // map [-1,1] -> [0,1]; OOB stays 0 (matches zero padding of the
                // transformed image in the reference conv)
                p4.x = (p4.x + 1.f) * 0.5f; p4.y = (p4.y + 1.f) * 0.5f;
                p4.z = (p4.z + 1.f) * 0.5f; p4.w = (p4.w + 1.f) * 0.5f;
                a4.x = (a4.x + 1.f) * 0.5f; a4.y = (a4.y + 1.f) * 0.5f;
                a4.z = (a4.z + 1.f) * 0.5f; a4.w = (a4.w + 1.f) * 0.5f;
                b4.x = (b4.x + 1.f) * 0.5f; b4.y = (b4.y + 1.f) * 0.5f;
                b4.z = (b4.z + 1.f) * 0.5f; b4.w = (b4.w + 1.f) * 0.5f;
            }
            const float pe[4] = {p4.x, p4.y, p4.z, p4.w};
            const float ae[4] = {a4.x, a4.y, a4.z, a4.w};
            const float be[4] = {b4.x, b4.y, b4.z, b4.w};
            #pragma unroll
            for (int e = 0; e < 4; ++e) {
                const int i = 4 * w + e;
                if (i < 3 || i >= 17) continue;
                const int t = i - 3;                 // window position 0..13
                const float p = pe[e], a = ae[e], b = be[e];
                const float pp = p * p, aa = a * a, bb = b * b;
                const float pa = p * a, pb = p * b;
                #pragma unroll
                for (int k = 0; k < 4; ++k) {
                    const int j = t - k;             // tap index
                    if (j < 0 || j > 10) continue;
                    const float wt = g[j];
                    accs[k][0] += wt * p;  accs[k][1] += wt * a;
                    accs[k][2] += wt * b;  accs[k][3] += wt * pp;
                    accs[k][4] += wt * aa; accs[k][5] += wt * bb;
                    accs[k][6] += wt * pa; accs[k][7] += wt * pb;
                }
            }
        }
        #pragma unroll
        for (int k = 0; k < 4; ++k) {
            const int sc = swz(4 * cg + k);
            h4a[r * HP + sc] =
                make_float4(accs[k][0], accs[k][1], accs[k][2], accs[k][3]);
            h4b[r * HP + sc] =
                make_float4(accs[k][4], accs[k][5], accs[k][6], accs[k][7]);
        }
    }
    __syncthreads();

    // ---------------- vertical pass + SSIM, 2 consecutive rows per thread ----
    const float C1v = 1e-4f;
    const float C2v = 9e-4f;
    float lsum = 0.f;
    {
        const int c  = tid & 31;
        const int rg = tid >> 5;          // 0..7
        const int R0 = rg * 2;
        const int sc = swz(c);

        float m[2][8];
        #pragma unroll
        for (int k = 0; k < 2; ++k)
            #pragma unroll
            for (int q = 0; q < 8; ++q) m[k][q] = 0.f;

        #pragma unroll
        for (int j = 0; j < 12; ++j) {
            const float4 va = h4a[(R0 + j) * HP + sc];
            const float4 vb = h4b[(R0 + j) * HP + sc];
            #pragma unroll
            for (int k = 0; k < 2; ++k) {
                const int t = j - k;                 // tap index
                if (t < 0 || t > 10) continue;
                const float wt = g[t];
                m[k][0] += wt * va.x; m[k][1] += wt * va.y;
                m[k][2] += wt * va.z; m[k][3] += wt * va.w;
                m[k][4] += wt * vb.x; m[k][5] += wt * vb.y;
                m[k][6] += wt * vb.z; m[k][7] += wt * vb.w;
            }
        }
        #pragma unroll
        for (int k = 0; k < 2; ++k) {
            const float mp = m[k][0], ma = m[k][1], mb = m[k][2];
            const float mpp = m[k][3], maa = m[k][4], mbb = m[k][5];
            const float mpa = m[k][6], mpb = m[k][7];
            const float mp2 = mp * mp, ma2 = ma * ma, mb2 = mb * mb;
            const float s_p  = mpp - mp2;
            const float s_a  = maa - ma2;
            const float s_b  = mbb - mb2;
            const float s_pa = mpa - mp * ma;
            const float s_pb = mpb - mp * mb;
            const float na = (2.f * mp * ma + C1v) * (2.f * s_pa + C2v);
            const float da = (mp2 + ma2 + C1v) * (s_p + s_a + C2v);
            const float nb = (2.f * mp * mb + C1v) * (2.f * s_pb + C2v);
            const float db = (mp2 + mb2 + C1v) * (s_p + s_b + C2v);
            lsum += na / da + nb / db;
        }
    }

    // ---------------- block reduction -> one atomic; last block finalizes ----
    lsum = wave_reduce(lsum);
    if ((tid & 63) == 0) red[tid >> 6] = lsum;
    __syncthreads();
    if (tid == 0) {
        float s = 0.f;
        #pragma unroll
        for (int i = 0; i < NT / 64; ++i) s += red[i];
        atomicAdd(&acc_ws[0], s);
        __threadfence();
        unsigned prev = atomicAdd((unsigned*)&acc_ws[1], 1u);
        if (prev == (unsigned)(NBLK - 1)) {
            float total = atomicAdd(&acc_ws[0], 0.f);  // coherent read of full sum
            out[0] = 1.f - total * invTwoN;
        }
    }
}

extern "C" void kernel_launch(void* const* d_in, const int* in_sizes, int n_in,
                              void* d_out, int out_size, void* d_ws, size_t ws_size,
                              hipStream_t stream) {
    const float* fused = (const float*)d_in[0];
    const float* img_a = (const float*)d_in[1];
    const float* img_b = (const float*)d_in[2];
    float* out = (float*)d_out;
    float* acc = (float*)d_ws;

    hipMemsetAsync(acc, 0, 2 * sizeof(float), stream);

    const float invTwoN = 1.f / (2.f * 16.f * (float)IMW * (float)IMH);
    dim3 grid(IMW / TW, IMH / TH, 16);
    ssim_main_kernel<<<grid, NT, 0, stream>>>(fused, img_a, img_b, acc, out, invTwoN);
}

// Round 4
// 128.054 us; speedup vs baseline: 2.5514x; 2.5514x over previous
//
#include <hip/hip_runtime.h>

#define NT 256
#define TW 32
#define TH 16
#define IH (TH + 10)   // 26 h-pass rows
#define HP 33          // LDS row stride in float4 units
#define IMW 512
#define IMH 512
#define NSLOT 64       // hashed accumulator slots
#define SLOTSTRIDE 16  // floats between slots (64 B -> no same-line bouncing)

__device__ __forceinline__ float wave_reduce(float v) {
    #pragma unroll
    for (int off = 32; off > 0; off >>= 1)
        v += __shfl_down(v, off, 64);
    return v;
}

// LDS column swizzle: breaks the 4-way bank conflict of stride-4-float4 store
// lanes while keeping the v-pass consecutive-lane reads conflict-free.
// (R2->R3: SQ_LDS_BANK_CONFLICT 4.13M -> 0.)
__device__ __forceinline__ int swz(int i) { return i ^ (i >> 3); }

// Gaussian 1-D weights for ws=11, sigma=1.5 (separable outer product == ref 2-D kernel)
#define G0 0.00102838f
#define G1 0.00759840f
#define G2 0.03600077f
#define G3 0.10936070f
#define G4 0.21300590f
#define G5 0.26601190f

__global__ __launch_bounds__(NT, 5) void ssim_main_kernel(
    const float* __restrict__ fused,
    const float* __restrict__ img_a,
    const float* __restrict__ img_b,
    float* __restrict__ acc_slots)
{
    // h-pass results, AoS float4: h4a = (p, a, b, pp), h4b = (aa, bb, pa, pb)
    __shared__ float4 h4a[IH * HP];
    __shared__ float4 h4b[IH * HP];
    __shared__ float red[NT / 64];

    const float g[11] = {G0, G1, G2, G3, G4, G5, G4, G3, G2, G1, G0};

    const int tid = threadIdx.x;
    const int x0 = blockIdx.x * TW;
    const int y0 = blockIdx.y * TH;
    const size_t ioff = (size_t)blockIdx.z * IMW * IMH;
    const float* Fp = fused + ioff;
    const float* Ap = img_a + ioff;
    const float* Bp = img_b + ioff;

    // ---------------- horizontal pass: global (L1/L2) -> registers -> LDS ----
    // task = (row r in [0,IH), col-group cg in [0,8)); 4 output cols per task.
    // Load 5 aligned float4 chunks at xbase = x0+4cg-8 (elements i=0..19, used
    // i in [3,17)). Products computed once per loaded element.
    if (tid < IH * 8) {
        const int r  = tid >> 3;
        const int cg = tid & 7;
        const int gy = y0 + r - 5;
        const bool yok = (gy >= 0) && (gy < IMH);

        float accs[4][8];
        #pragma unroll
        for (int k = 0; k < 4; ++k)
            #pragma unroll
            for (int q = 0; q < 8; ++q) accs[k][q] = 0.f;

        const int xbase = x0 + 4 * cg - 8;
        #pragma unroll
        for (int w = 0; w < 5; ++w) {
            const int xc = xbase + 4 * w;
            float4 p4 = {0.f, 0.f, 0.f, 0.f};
            float4 a4 = {0.f, 0.f, 0.f, 0.f};
            float4 b4 = {0.f, 0.f, 0.f, 0.f};
            if (yok && xc >= 0 && xc < IMW) {
                const size_t o = ((size_t)gy * IMW + xc) >> 2;  // float4 index
                p4 = ((const float4*)Fp)[o];
                a4 = ((const float4*)Ap)[o];
                b4 = ((const float4*)Bp)[o];
                // map [-1,1] -> [0,1]; OOB stays 0 (matches zero padding of the
                // transformed image in the reference conv)
                p4.x = (p4.x + 1.f) * 0.5f; p4.y = (p4.y + 1.f) * 0.5f;
                p4.z = (p4.z + 1.f) * 0.5f; p4.w = (p4.w + 1.f) * 0.5f;
                a4.x = (a4.x + 1.f) * 0.5f; a4.y = (a4.y + 1.f) * 0.5f;
                a4.z = (a4.z + 1.f) * 0.5f; a4.w = (a4.w + 1.f) * 0.5f;
                b4.x = (b4.x + 1.f) * 0.5f; b4.y = (b4.y + 1.f) * 0.5f;
                b4.z = (b4.z + 1.f) * 0.5f; b4.w = (b4.w + 1.f) * 0.5f;
            }
            const float pe[4] = {p4.x, p4.y, p4.z, p4.w};
            const float ae[4] = {a4.x, a4.y, a4.z, a4.w};
            const float be[4] = {b4.x, b4.y, b4.z, b4.w};
            #pragma unroll
            for (int e = 0; e < 4; ++e) {
                const int i = 4 * w + e;
                if (i < 3 || i >= 17) continue;
                const int t = i - 3;                 // window position 0..13
                const float p = pe[e], a = ae[e], b = be[e];
                const float pp = p * p, aa = a * a, bb = b * b;
                const float pa = p * a, pb = p * b;
                #pragma unroll
                for (int k = 0; k < 4; ++k) {
                    const int j = t - k;             // tap index
                    if (j < 0 || j > 10) continue;
                    const float wt = g[j];
                    accs[k][0] += wt * p;  accs[k][1] += wt * a;
                    accs[k][2] += wt * b;  accs[k][3] += wt * pp;
                    accs[k][4] += wt * aa; accs[k][5] += wt * bb;
                    accs[k][6] += wt * pa; accs[k][7] += wt * pb;
                }
            }
        }
        #pragma unroll
        for (int k = 0; k < 4; ++k) {
            const int sc = swz(4 * cg + k);
            h4a[r * HP + sc] =
                make_float4(accs[k][0], accs[k][1], accs[k][2], accs[k][3]);
            h4b[r * HP + sc] =
                make_float4(accs[k][4], accs[k][5], accs[k][6], accs[k][7]);
        }
    }
    __syncthreads();

    // ---------------- vertical pass + SSIM, 2 consecutive rows per thread ----
    const float C1v = 1e-4f;
    const float C2v = 9e-4f;
    float lsum = 0.f;
    {
        const int c  = tid & 31;
        const int rg = tid >> 5;          // 0..7
        const int R0 = rg * 2;
        const int sc = swz(c);

        float m[2][8];
        #pragma unroll
        for (int k = 0; k < 2; ++k)
            #pragma unroll
            for (int q = 0; q < 8; ++q) m[k][q] = 0.f;

        #pragma unroll
        for (int j = 0; j < 12; ++j) {
            const float4 va = h4a[(R0 + j) * HP + sc];
            const float4 vb = h4b[(R0 + j) * HP + sc];
            #pragma unroll
            for (int k = 0; k < 2; ++k) {
                const int t = j - k;                 // tap index
                if (t < 0 || t > 10) continue;
                const float wt = g[t];
                m[k][0] += wt * va.x; m[k][1] += wt * va.y;
                m[k][2] += wt * va.z; m[k][3] += wt * va.w;
                m[k][4] += wt * vb.x; m[k][5] += wt * vb.y;
                m[k][6] += wt * vb.z; m[k][7] += wt * vb.w;
            }
        }
        #pragma unroll
        for (int k = 0; k < 2; ++k) {
            const float mp = m[k][0], ma = m[k][1], mb = m[k][2];
            const float mpp = m[k][3], maa = m[k][4], mbb = m[k][5];
            const float mpa = m[k][6], mpb = m[k][7];
            const float mp2 = mp * mp, ma2 = ma * ma, mb2 = mb * mb;
            const float s_p  = mpp - mp2;
            const float s_a  = maa - ma2;
            const float s_b  = mbb - mb2;
            const float s_pa = mpa - mp * ma;
            const float s_pb = mpb - mp * mb;
            const float na = (2.f * mp * ma + C1v) * (2.f * s_pa + C2v);
            const float da = (mp2 + ma2 + C1v) * (s_p + s_a + C2v);
            const float nb = (2.f * mp * mb + C1v) * (2.f * s_pb + C2v);
            const float db = (mp2 + mb2 + C1v) * (s_p + s_b + C2v);
            lsum += na / da + nb / db;
        }
    }

    // ---------------- block reduction -> one hashed-slot atomic per block ----
    // NO device-scope fence, NO done-counter (R3 post-mortem: the per-block
    // __threadfence + same-cacheline counter serialized retirement, 74->280us).
    lsum = wave_reduce(lsum);
    if ((tid & 63) == 0) red[tid >> 6] = lsum;
    __syncthreads();
    if (tid == 0) {
        float s = 0.f;
        #pragma unroll
        for (int i = 0; i < NT / 64; ++i) s += red[i];
        const int lin = blockIdx.x + (int)gridDim.x * (blockIdx.y + (int)gridDim.y * blockIdx.z);
        atomicAdd(&acc_slots[(lin & (NSLOT - 1)) * SLOTSTRIDE], s);
    }
}

__global__ void ssim_finalize_kernel(const float* __restrict__ acc_slots,
                                     float* __restrict__ out, float invTwoN) {
    float v = acc_slots[threadIdx.x * SLOTSTRIDE];   // 64 threads, one slot each
    v = wave_reduce(v);
    if (threadIdx.x == 0) out[0] = 1.f - v * invTwoN;
}

extern "C" void kernel_launch(void* const* d_in, const int* in_sizes, int n_in,
                              void* d_out, int out_size, void* d_ws, size_t ws_size,
                              hipStream_t stream) {
    const float* fused = (const float*)d_in[0];
    const float* img_a = (const float*)d_in[1];
    const float* img_b = (const float*)d_in[2];
    float* out = (float*)d_out;
    float* acc = (float*)d_ws;

    hipMemsetAsync(acc, 0, NSLOT * SLOTSTRIDE * sizeof(float), stream);

    dim3 grid(IMW / TW, IMH / TH, 16);
    ssim_main_kernel<<<grid, NT, 0, stream>>>(fused, img_a, img_b, acc);

    const float invTwoN = 1.f / (2.f * 16.f * (float)IMW * (float)IMH);
    ssim_finalize_kernel<<<1, 64, 0, stream>>>(acc, out, invTwoN);
}

// Round 5
// 123.989 us; speedup vs baseline: 2.6351x; 1.0328x over previous
//
#include <hip/hip_runtime.h>

#define NT 256
#define TW 32
#define TH 16
#define IH (TH + 10)   // 26 h-pass rows
#define HP 33          // LDS row stride in float4 units (odd -> conflict-free with swz)
#define IMW 512
#define IMH 512
#define NSLOT 64       // hashed accumulator slots
#define SLOTSTRIDE 16  // floats between slots (64 B -> no same-line bouncing)

__device__ __forceinline__ float wave_reduce(float v) {
    #pragma unroll
    for (int off = 32; off > 0; off >>= 1)
        v += __shfl_down(v, off, 64);
    return v;
}

// LDS column swizzle: breaks the 4-way bank conflict of stride-4-float4 store
// lanes while keeping the v-pass consecutive-lane reads conflict-free.
// (R2->R3: SQ_LDS_BANK_CONFLICT 4.13M -> 0. Requires odd HP.)
__device__ __forceinline__ int swz(int i) { return i ^ (i >> 3); }

// Gaussian 1-D weights for ws=11, sigma=1.5 (separable outer product == ref 2-D kernel)
#define G0 0.00102838f
#define G1 0.00759840f
#define G2 0.03600077f
#define G3 0.10936070f
#define G4 0.21300590f
#define G5 0.26601190f

// Horizontal pass. BORDER=false (82% of blocks) has NO bounds logic at all:
// unconditional float4 loads, straight-line code. OOB lanes in the BORDER
// path are filled with -1.0, which the (x+1)*0.5 transform maps to exactly
// 0 == reference zero-padding of the transformed image.
template<bool BORDER>
__device__ __forceinline__ void h_pass(
    const float* __restrict__ Fp, const float* __restrict__ Ap,
    const float* __restrict__ Bp, int x0, int y0, int tid,
    float4* __restrict__ h4a, float4* __restrict__ h4b)
{
    const float g[11] = {G0, G1, G2, G3, G4, G5, G4, G3, G2, G1, G0};
    if (tid >= IH * 8) return;
    const int r  = tid >> 3;
    const int cg = tid & 7;
    const int gy = y0 + r - 5;
    bool yok = true;
    if (BORDER) yok = (gy >= 0) && (gy < IMH);

    float accs[4][8];
    #pragma unroll
    for (int k = 0; k < 4; ++k)
        #pragma unroll
        for (int q = 0; q < 8; ++q) accs[k][q] = 0.f;

    const int xbase = x0 + 4 * cg - 8;
    #pragma unroll
    for (int w = 0; w < 5; ++w) {
        const int xc = xbase + 4 * w;
        float4 p4 = {-1.f, -1.f, -1.f, -1.f};
        float4 a4 = {-1.f, -1.f, -1.f, -1.f};
        float4 b4 = {-1.f, -1.f, -1.f, -1.f};
        bool ld = true;
        if (BORDER) ld = yok && (xc >= 0) && (xc < IMW);
        if (ld) {
            const size_t o = ((size_t)gy * IMW + xc) >> 2;  // float4 index
            p4 = ((const float4*)Fp)[o];
            a4 = ((const float4*)Ap)[o];
            b4 = ((const float4*)Bp)[o];
        }
        const float pe[4] = {p4.x, p4.y, p4.z, p4.w};
        const float ae[4] = {a4.x, a4.y, a4.z, a4.w};
        const float be[4] = {b4.x, b4.y, b4.z, b4.w};
        #pragma unroll
        for (int e = 0; e < 4; ++e) {
            const int i = 4 * w + e;
            if (i < 3 || i >= 17) continue;        // unused alignment slack
            const int t = i - 3;                   // window position 0..13
            // transform only the 14 used elements (was: all 20)
            const float p = fmaf(pe[e], 0.5f, 0.5f);
            const float a = fmaf(ae[e], 0.5f, 0.5f);
            const float b = fmaf(be[e], 0.5f, 0.5f);
            const float pp = p * p, aa = a * a, bb = b * b;
            const float pa = p * a, pb = p * b;
            #pragma unroll
            for (int k = 0; k < 4; ++k) {
                const int j = t - k;               // tap index
                if (j < 0 || j > 10) continue;
                const float wt = g[j];
                accs[k][0] += wt * p;  accs[k][1] += wt * a;
                accs[k][2] += wt * b;  accs[k][3] += wt * pp;
                accs[k][4] += wt * aa; accs[k][5] += wt * bb;
                accs[k][6] += wt * pa; accs[k][7] += wt * pb;
            }
        }
    }
    #pragma unroll
    for (int k = 0; k < 4; ++k) {
        const int sc = swz(4 * cg + k);
        h4a[r * HP + sc] =
            make_float4(accs[k][0], accs[k][1], accs[k][2], accs[k][3]);
        h4b[r * HP + sc] =
            make_float4(accs[k][4], accs[k][5], accs[k][6], accs[k][7]);
    }
}

__global__ __launch_bounds__(NT, 5) void ssim_main_kernel(
    const float* __restrict__ fused,
    const float* __restrict__ img_a,
    const float* __restrict__ img_b,
    float* __restrict__ acc_slots)
{
    // h-pass results, AoS float4: h4a = (p, a, b, pp), h4b = (aa, bb, pa, pb)
    __shared__ float4 h4a[IH * HP];
    __shared__ float4 h4b[IH * HP];
    __shared__ float red[NT / 64];

    const float g[11] = {G0, G1, G2, G3, G4, G5, G4, G3, G2, G1, G0};

    const int tid = threadIdx.x;
    const int x0 = blockIdx.x * TW;
    const int y0 = blockIdx.y * TH;
    const size_t ioff = (size_t)blockIdx.z * IMW * IMH;
    const float* Fp = fused + ioff;
    const float* Ap = img_a + ioff;
    const float* Bp = img_b + ioff;

    // Border blocks: x-tile touches image edge (blockIdx.x 0 or last) or the
    // y-halo goes OOB (blockIdx.y 0 or last). 82% of blocks take the
    // check-free interior path.
    const bool border = (blockIdx.x == 0) | (blockIdx.x == gridDim.x - 1) |
                        (blockIdx.y == 0) | (blockIdx.y == gridDim.y - 1);
    if (border) h_pass<true >(Fp, Ap, Bp, x0, y0, tid, h4a, h4b);
    else        h_pass<false>(Fp, Ap, Bp, x0, y0, tid, h4a, h4b);
    __syncthreads();

    // ---------------- vertical pass + SSIM, 2 consecutive rows per thread ----
    const float C1v = 1e-4f;
    const float C2v = 9e-4f;
    float lsum = 0.f;
    {
        const int c  = tid & 31;
        const int rg = tid >> 5;          // 0..7
        const int R0 = rg * 2;
        const int sc = swz(c);

        float m[2][8];
        #pragma unroll
        for (int k = 0; k < 2; ++k)
            #pragma unroll
            for (int q = 0; q < 8; ++q) m[k][q] = 0.f;

        #pragma unroll
        for (int j = 0; j < 12; ++j) {
            const float4 va = h4a[(R0 + j) * HP + sc];
            const float4 vb = h4b[(R0 + j) * HP + sc];
            #pragma unroll
            for (int k = 0; k < 2; ++k) {
                const int t = j - k;                 // tap index
                if (t < 0 || t > 10) continue;
                const float wt = g[t];
                m[k][0] += wt * va.x; m[k][1] += wt * va.y;
                m[k][2] += wt * va.z; m[k][3] += wt * va.w;
                m[k][4] += wt * vb.x; m[k][5] += wt * vb.y;
                m[k][6] += wt * vb.z; m[k][7] += wt * vb.w;
            }
        }
        #pragma unroll
        for (int k = 0; k < 2; ++k) {
            const float mp = m[k][0], ma = m[k][1], mb = m[k][2];
            const float mpp = m[k][3], maa = m[k][4], mbb = m[k][5];
            const float mpa = m[k][6], mpb = m[k][7];
            const float mp2 = mp * mp, ma2 = ma * ma, mb2 = mb * mb;
            const float s_p  = mpp - mp2;
            const float s_a  = maa - ma2;
            const float s_b  = mbb - mb2;
            const float s_pa = mpa - mp * ma;
            const float s_pb = mpb - mp * mb;
            const float na = (2.f * mp * ma + C1v) * (2.f * s_pa + C2v);
            const float da = (mp2 + ma2 + C1v) * (s_p + s_a + C2v);
            const float nb = (2.f * mp * mb + C1v) * (2.f * s_pb + C2v);
            const float db = (mp2 + mb2 + C1v) * (s_p + s_b + C2v);
            // v_rcp_f32 (~1 ulp) instead of full-precision divide: saves
            // ~16 VALU/thread; error budget is 1.98e-2, rcp adds <1e-6.
            lsum += na * __builtin_amdgcn_rcpf(da)
                  + nb * __builtin_amdgcn_rcpf(db);
        }
    }

    // ---------------- block reduction -> one hashed-slot atomic per block ----
    // NO device-scope fence, NO done-counter (R3 post-mortem: per-block
    // __threadfence + same-cacheline counter serialized retirement, 74->280us).
    lsum = wave_reduce(lsum);
    if ((tid & 63) == 0) red[tid >> 6] = lsum;
    __syncthreads();
    if (tid == 0) {
        float s = 0.f;
        #pragma unroll
        for (int i = 0; i < NT / 64; ++i) s += red[i];
        const int lin = blockIdx.x + (int)gridDim.x * (blockIdx.y + (int)gridDim.y * blockIdx.z);
        atomicAdd(&acc_slots[(lin & (NSLOT - 1)) * SLOTSTRIDE], s);
    }
}

__global__ void ssim_finalize_kernel(const float* __restrict__ acc_slots,
                                     float* __restrict__ out, float invTwoN) {
    float v = acc_slots[threadIdx.x * SLOTSTRIDE];   // 64 threads, one slot each
    v = wave_reduce(v);
    if (threadIdx.x == 0) out[0] = 1.f - v * invTwoN;
}

extern "C" void kernel_launch(void* const* d_in, const int* in_sizes, int n_in,
                              void* d_out, int out_size, void* d_ws, size_t ws_size,
                              hipStream_t stream) {
    const float* fused = (const float*)d_in[0];
    const float* img_a = (const float*)d_in[1];
    const float* img_b = (const float*)d_in[2];
    float* out = (float*)d_out;
    float* acc = (float*)d_ws;

    hipMemsetAsync(acc, 0, NSLOT * SLOTSTRIDE * sizeof(float), stream);

    dim3 grid(IMW / TW, IMH / TH, 16);
    ssim_main_kernel<<<grid, NT, 0, stream>>>(fused, img_a, img_b, acc);

    const float invTwoN = 1.f / (2.f * 16.f * (float)IMW * (float)IMH);
    ssim_finalize_kernel<<<1, 64, 0, stream>>>(acc, out, invTwoN);
}

// Round 6
// 119.000 us; speedup vs baseline: 2.7455x; 1.0419x over previous
//
#include <hip/hip_runtime.h>

#define NT 256
#define TW 32
#define TH 16
#define IH (TH + 10)   // 26 h-pass rows
#define HP 33          // LDS row stride in float4 units (odd -> conflict-free with swz)
#define IMW 512
#define IMH 512
#define NSLOT 64       // hashed accumulator slots
#define SLOTSTRIDE 16  // floats between slots (64 B -> no same-line bouncing)

// native 2-wide fp32 vector -> v_pk_fma_f32 / v_pk_mul_f32 on gfx950
typedef float f32x2 __attribute__((ext_vector_type(2)));

__device__ __forceinline__ float wave_reduce(float v) {
    #pragma unroll
    for (int off = 32; off > 0; off >>= 1)
        v += __shfl_down(v, off, 64);
    return v;
}

// LDS column swizzle: breaks the 4-way bank conflict of stride-4-float4 store
// lanes while keeping the v-pass consecutive-lane reads conflict-free.
// (R2->R3: SQ_LDS_BANK_CONFLICT 4.13M -> 0. Requires odd HP.)
__device__ __forceinline__ int swz(int i) { return i ^ (i >> 3); }

// Gaussian 1-D weights for ws=11, sigma=1.5 (separable outer product == ref 2-D kernel)
#define G0 0.00102838f
#define G1 0.00759840f
#define G2 0.03600077f
#define G3 0.10936070f
#define G4 0.21300590f
#define G5 0.26601190f

// Horizontal pass. BORDER=false (82% of blocks) has NO bounds logic at all.
// OOB lanes in the BORDER path are filled with -1.0, which (x+1)*0.5 maps to
// exactly 0 == reference zero-padding of the transformed image.
// Accumulator pairing (packed fp32): A0={p,a} A1={b,bb} A2={pp,aa} A3={pa,pb}
// LDS layout: h4a=(p,a,b,bb), h4b=(pp,aa,pa,pb).
template<bool BORDER>
__device__ __forceinline__ void h_pass(
    const float* __restrict__ Fp, const float* __restrict__ Ap,
    const float* __restrict__ Bp, int x0, int y0, int tid,
    float4* __restrict__ h4a, float4* __restrict__ h4b)
{
    const float g[11] = {G0, G1, G2, G3, G4, G5, G4, G3, G2, G1, G0};
    if (tid >= IH * 8) return;
    const int r  = tid >> 3;
    const int cg = tid & 7;
    const int gy = y0 + r - 5;
    bool yok = true;
    if (BORDER) yok = (gy >= 0) && (gy < IMH);

    f32x2 accs[4][4];
    #pragma unroll
    for (int k = 0; k < 4; ++k)
        #pragma unroll
        for (int q = 0; q < 4; ++q) accs[k][q] = (f32x2){0.f, 0.f};

    const int xbase = x0 + 4 * cg - 8;
    #pragma unroll
    for (int w = 0; w < 5; ++w) {
        const int xc = xbase + 4 * w;
        float4 p4 = {-1.f, -1.f, -1.f, -1.f};
        float4 a4 = {-1.f, -1.f, -1.f, -1.f};
        float4 b4 = {-1.f, -1.f, -1.f, -1.f};
        bool ld = true;
        if (BORDER) ld = yok && (xc >= 0) && (xc < IMW);
        if (ld) {
            const size_t o = ((size_t)gy * IMW + xc) >> 2;  // float4 index
            p4 = ((const float4*)Fp)[o];
            a4 = ((const float4*)Ap)[o];
            b4 = ((const float4*)Bp)[o];
        }
        const float pe[4] = {p4.x, p4.y, p4.z, p4.w};
        const float ae[4] = {a4.x, a4.y, a4.z, a4.w};
        const float be[4] = {b4.x, b4.y, b4.z, b4.w};
        #pragma unroll
        for (int e = 0; e < 4; ++e) {
            const int i = 4 * w + e;
            if (i < 3 || i >= 17) continue;        // unused alignment slack
            const int t = i - 3;                   // window position 0..13
            // transform only the 14 used elements
            const float p = fmaf(pe[e], 0.5f, 0.5f);
            const float a = fmaf(ae[e], 0.5f, 0.5f);
            const float b = fmaf(be[e], 0.5f, 0.5f);
            // packed products
            const f32x2 v_pa   = {p, a};
            const f32x2 v_ab   = {a, b};
            const f32x2 v_pp2  = {p, p};
            const f32x2 v_ppaa = v_pa * v_pa;      // {pp, aa} v_pk_mul_f32
            const f32x2 v_papb = v_pp2 * v_ab;     // {pa, pb} v_pk_mul_f32
            const f32x2 v_bbb  = {b, b * b};       // {b, bb}
            #pragma unroll
            for (int k = 0; k < 4; ++k) {
                const int j = t - k;               // tap index
                if (j < 0 || j > 10) continue;
                const f32x2 w2 = {g[j], g[j]};
                accs[k][0] += w2 * v_pa;           // v_pk_fma_f32
                accs[k][1] += w2 * v_bbb;
                accs[k][2] += w2 * v_ppaa;
                accs[k][3] += w2 * v_papb;
            }
        }
    }
    #pragma unroll
    for (int k = 0; k < 4; ++k) {
        const int sc = swz(4 * cg + k);
        h4a[r * HP + sc] = make_float4(accs[k][0].x, accs[k][0].y,
                                       accs[k][1].x, accs[k][1].y);
        h4b[r * HP + sc] = make_float4(accs[k][2].x, accs[k][2].y,
                                       accs[k][3].x, accs[k][3].y);
    }
}

__global__ __launch_bounds__(NT, 5) void ssim_main_kernel(
    const float* __restrict__ fused,
    const float* __restrict__ img_a,
    const float* __restrict__ img_b,
    float* __restrict__ acc_slots)
{
    // h-pass results: h4a=(p,a,b,bb), h4b=(pp,aa,pa,pb)
    __shared__ float4 h4a[IH * HP];
    __shared__ float4 h4b[IH * HP];
    __shared__ float red[NT / 64];

    const float g[11] = {G0, G1, G2, G3, G4, G5, G4, G3, G2, G1, G0};

    const int tid = threadIdx.x;
    const int x0 = blockIdx.x * TW;
    const int y0 = blockIdx.y * TH;
    const size_t ioff = (size_t)blockIdx.z * IMW * IMH;
    const float* Fp = fused + ioff;
    const float* Ap = img_a + ioff;
    const float* Bp = img_b + ioff;

    const bool border = (blockIdx.x == 0) | (blockIdx.x == gridDim.x - 1) |
                        (blockIdx.y == 0) | (blockIdx.y == gridDim.y - 1);
    if (border) h_pass<true >(Fp, Ap, Bp, x0, y0, tid, h4a, h4b);
    else        h_pass<false>(Fp, Ap, Bp, x0, y0, tid, h4a, h4b);
    __syncthreads();

    // ---------------- vertical pass + SSIM, 2 consecutive rows per thread ----
    const float C1v = 1e-4f;
    const float C2v = 9e-4f;
    float lsum = 0.f;
    {
        const int c  = tid & 31;
        const int rg = tid >> 5;          // 0..7
        const int R0 = rg * 2;
        const int sc = swz(c);

        f32x2 m2[2][4];
        #pragma unroll
        for (int k = 0; k < 2; ++k)
            #pragma unroll
            for (int q = 0; q < 4; ++q) m2[k][q] = (f32x2){0.f, 0.f};

        #pragma unroll
        for (int j = 0; j < 12; ++j) {
            const float4 va = h4a[(R0 + j) * HP + sc];
            const float4 vb = h4b[(R0 + j) * HP + sc];
            const f32x2 va01 = {va.x, va.y};
            const f32x2 va23 = {va.z, va.w};
            const f32x2 vb01 = {vb.x, vb.y};
            const f32x2 vb23 = {vb.z, vb.w};
            #pragma unroll
            for (int k = 0; k < 2; ++k) {
                const int t = j - k;                 // tap index
                if (t < 0 || t > 10) continue;
                const f32x2 w2 = {g[t], g[t]};
                m2[k][0] += w2 * va01;               // v_pk_fma_f32
                m2[k][1] += w2 * va23;
                m2[k][2] += w2 * vb01;
                m2[k][3] += w2 * vb23;
            }
        }
        #pragma unroll
        for (int k = 0; k < 2; ++k) {
            const float mp  = m2[k][0].x, ma  = m2[k][0].y;
            const float mb  = m2[k][1].x, mbb = m2[k][1].y;
            const float mpp = m2[k][2].x, maa = m2[k][2].y;
            const float mpa = m2[k][3].x, mpb = m2[k][3].y;
            const float mp2 = mp * mp, ma2 = ma * ma, mb2 = mb * mb;
            const float s_p  = mpp - mp2;
            const float s_a  = maa - ma2;
            const float s_b  = mbb - mb2;
            const float s_pa = mpa - mp * ma;
            const float s_pb = mpb - mp * mb;
            const float na = (2.f * mp * ma + C1v) * (2.f * s_pa + C2v);
            const float da = (mp2 + ma2 + C1v) * (s_p + s_a + C2v);
            const float nb = (2.f * mp * mb + C1v) * (2.f * s_pb + C2v);
            const float db = (mp2 + mb2 + C1v) * (s_p + s_b + C2v);
            // v_rcp_f32 (~1 ulp) instead of divide; budget 1.98e-2 >> 1e-6
            lsum += na * __builtin_amdgcn_rcpf(da)
                  + nb * __builtin_amdgcn_rcpf(db);
        }
    }

    // ---------------- block reduction -> one hashed-slot atomic per block ----
    // NO device-scope fence, NO done-counter (R3: fence+counter serialized
    // retirement, 74->280us).
    lsum = wave_reduce(lsum);
    if ((tid & 63) == 0) red[tid >> 6] = lsum;
    __syncthreads();
    if (tid == 0) {
        float s = 0.f;
        #pragma unroll
        for (int i = 0; i < NT / 64; ++i) s += red[i];
        const int lin = blockIdx.x + (int)gridDim.x * (blockIdx.y + (int)gridDim.y * blockIdx.z);
        atomicAdd(&acc_slots[(lin & (NSLOT - 1)) * SLOTSTRIDE], s);
    }
}

__global__ void ssim_finalize_kernel(const float* __restrict__ acc_slots,
                                     float* __restrict__ out, float invTwoN) {
    float v = acc_slots[threadIdx.x * SLOTSTRIDE];   // 64 threads, one slot each
    v = wave_reduce(v);
    if (threadIdx.x == 0) out[0] = 1.f - v * invTwoN;
}

extern "C" void kernel_launch(void* const* d_in, const int* in_sizes, int n_in,
                              void* d_out, int out_size, void* d_ws, size_t ws_size,
                              hipStream_t stream) {
    const float* fused = (const float*)d_in[0];
    const float* img_a = (const float*)d_in[1];
    const float* img_b = (const float*)d_in[2];
    float* out = (float*)d_out;
    float* acc = (float*)d_ws;

    hipMemsetAsync(acc, 0, NSLOT * SLOTSTRIDE * sizeof(float), stream);

    dim3 grid(IMW / TW, IMH / TH, 16);
    ssim_main_kernel<<<grid, NT, 0, stream>>>(fused, img_a, img_b, acc);

    const float invTwoN = 1.f / (2.f * 16.f * (float)IMW * (float)IMH);
    ssim_finalize_kernel<<<1, 64, 0, stream>>>(acc, out, invTwoN);
}